// Round 1
// baseline (270.884 us; speedup 1.0000x reference)
//
#include <hip/hip_runtime.h>

#define B_ 256
#define S_ 512
#define V_ 50000
#define D_ 256
#define L_ 128
#define NG 512           // gemm blocks in fused1
#define NENC 256         // enc blocks (== B_)
#define NCH (V_ / 16)    // 3125 row-chunks of 16
#define NSPLIT 8
#define K2B (B_ * NSPLIT)

typedef __attribute__((ext_vector_type(8))) short short8;
typedef __attribute__((ext_vector_type(4))) float floatx4;

// ws layout (float units):
// [0..16)   ctrl: [3]=done (int)
// [16..272)  sqp[256]
// [272..528) kl[256]
// [528..784) cnt[256] (int)
// [784..784+65536) Q[256][256]
// [66320 .. +6400000) P (50000x256 bf16 = emb @ Wout)
#define OFF_SQP 16
#define OFF_KL  (OFF_SQP + 256)
#define OFF_CNT (OFF_KL + 256)
#define OFF_Q   (OFF_CNT + 256)
#define OFF_P   (OFF_Q + B_ * D_)

__device__ __forceinline__ unsigned short f2bf(float x) {
    unsigned u = __float_as_uint(x);
    u += 0x7FFFu + ((u >> 16) & 1u);
    return (unsigned short)(u >> 16);
}
__device__ __forceinline__ float bf2f(unsigned short u) {
    return __uint_as_float(((unsigned)u) << 16);
}
__device__ __forceinline__ short8 cvt8(float4 a, float4 b) {
    short8 r;
    r[0] = (short)f2bf(a.x); r[1] = (short)f2bf(a.y);
    r[2] = (short)f2bf(a.z); r[3] = (short)f2bf(a.w);
    r[4] = (short)f2bf(b.x); r[5] = (short)f2bf(b.y);
    r[6] = (short)f2bf(b.z); r[7] = (short)f2bf(b.w);
    return r;
}

// ---- K1: enc blocks (0..255) overlap with fused convert+P-GEMM blocks (256..767) ----
__global__ __launch_bounds__(512, 4) void fused1(
    const int* __restrict__ vocab, const int* __restrict__ order,
    const int* __restrict__ mask, const float* __restrict__ emb,
    const float* __restrict__ eps, const float* __restrict__ Wm,
    const float* __restrict__ bm, const float* __restrict__ Wv,
    const float* __restrict__ bv, const float* __restrict__ Wlin,
    const float* __restrict__ blin, const float* __restrict__ Wout,
    const float* __restrict__ bout, float* __restrict__ ws) {
    const int tid = threadIdx.x;
    if (blockIdx.x >= NENC) {
        // ================= GEMM role: P = bf16(emb) @ bf16(Wout) =================
        const int gb = blockIdx.x - NENC;
        if (gb == 0 && tid == 0) ((int*)ws)[3] = 0;  // reset done counter for scan2
        unsigned short* __restrict__ P = (unsigned short*)(ws + OFF_P);
        const int lane = tid & 63;
        const int wv = tid >> 6;          // 8 waves, 32 output cols each
        const int lo = lane & 15, hi = lane >> 4;
        const int colbase = wv * 32;
        // B fragments straight from f32 Wout (L2-resident after first touch)
        short8 bfr[2][8];
#pragma unroll
        for (int nt = 0; nt < 2; ++nt)
#pragma unroll
            for (int kk = 0; kk < 8; ++kk) {
                const float* wp = Wout + (size_t)(hi * 8 + kk * 32) * D_ +
                                  colbase + nt * 16 + lo;
                short8 w;
#pragma unroll
                for (int e = 0; e < 8; ++e) w[e] = (short)f2bf(wp[(size_t)e * D_]);
                bfr[nt][kk] = w;
            }
        for (int ch = gb; ch < NCH; ch += NG) {
            const float* abase = emb + (size_t)(ch * 16 + lo) * D_ + hi * 8;
            floatx4 acc0 = {0.f, 0.f, 0.f, 0.f}, acc1 = {0.f, 0.f, 0.f, 0.f};
#pragma unroll
            for (int kh = 0; kh < 2; ++kh) {   // two half-K phases to bound live f32 regs
                float4 t0[4], t1[4];
#pragma unroll
                for (int q = 0; q < 4; ++q) {
                    const float* ap = abase + (kh * 4 + q) * 32;
                    t0[q] = *(const float4*)ap;
                    t1[q] = *(const float4*)(ap + 4);
                }
#pragma unroll
                for (int q = 0; q < 4; ++q) {
                    short8 av = cvt8(t0[q], t1[q]);
                    acc0 = __builtin_amdgcn_mfma_f32_16x16x32_bf16(
                        av, bfr[0][kh * 4 + q], acc0, 0, 0, 0);
                    acc1 = __builtin_amdgcn_mfma_f32_16x16x32_bf16(
                        av, bfr[1][kh * 4 + q], acc1, 0, 0, 0);
                }
            }
#pragma unroll
            for (int r = 0; r < 4; ++r) {
                unsigned short* prow =
                    P + (size_t)(ch * 16 + hi * 4 + r) * D_ + colbase + lo;
                prow[0] = f2bf(acc0[r]);
                prow[16] = f2bf(acc1[r]);
            }
        }
        return;
    }
    // ================= ENC role: phases 1-3 of old enclat, f32 emb gathers =================
    __shared__ int s_id1[S_], s_id2[S_];
    __shared__ float4 s_part[7 * 64];
    __shared__ float s_enc[D_];
    __shared__ float s_mean[L_], s_lv[L_], s_z[L_], s_mem[D_];
    __shared__ float s_red[256];
    __shared__ int s_cnt;
    const int b = blockIdx.x;
    if (tid == 0) s_cnt = 0;
    __syncthreads();
    {   // phase 1: ids + cnt (512 threads cover S_)
        const int j = tid;
        const int mk = mask[b * S_ + j];
        int id1 = 0, id2 = 0;
        if (mk) {
            id1 = vocab[b * S_ + j];
            if (j == 0) {
                id2 = 1;  // BOS
            } else {
                int oi = order[(size_t)(b * S_ + j) * 6];
                if (oi == -1) oi = 1;
                id2 = mask[b * S_ + oi] ? vocab[b * S_ + oi] : 0;
            }
        }
        s_id1[j] = id1;
        s_id2[j] = id2;
        unsigned long long bal = __ballot(mk != 0);
        if ((tid & 63) == 0) atomicAdd(&s_cnt, __popcll(bal));
    }
    __syncthreads();
    const int cnt = s_cnt;
    // phase 2: mean of emb[id1]+emb[id2] over valid prefix, f32 gathers
    const int jg = tid >> 6, d4 = tid & 63;
    const float4* eb4 = (const float4*)emb;
    float4 a = {0.f, 0.f, 0.f, 0.f};
#pragma unroll 4
    for (int j = jg; j < cnt; j += 8) {
        float4 x = eb4[(size_t)s_id1[j] * 64 + d4];
        float4 y = eb4[(size_t)s_id2[j] * 64 + d4];
        a.x += x.x + y.x; a.y += x.y + y.y;
        a.z += x.z + y.z; a.w += x.w + y.w;
    }
    if (jg) s_part[(jg - 1) * 64 + d4] = a;
    __syncthreads();
    if (jg == 0) {
#pragma unroll
        for (int g = 0; g < 7; ++g) {
            float4 p = s_part[g * 64 + d4];
            a.x += p.x; a.y += p.y; a.z += p.z; a.w += p.w;
        }
        const float inv = 1.f / fmaxf((float)cnt, 1.f);
        a.x *= inv; a.y *= inv; a.z *= inv; a.w *= inv;
        ((float4*)s_enc)[d4] = a;
    }
    __syncthreads();
    // phase 3: latent chain -> Q[b], kl[b], cnt[b]
    if (tid < 256) {
        const int l = tid & (L_ - 1);
        const float* W = (tid < L_) ? Wm : Wv;
        const float* bb = (tid < L_) ? bm : bv;
        float dot = bb[l];
        for (int d = 0; d < D_; ++d) dot = fmaf(s_enc[d], W[d * L_ + l], dot);
        if (tid < L_) s_mean[l] = dot; else s_lv[l] = dot;
    }
    __syncthreads();
    float klp = 0.f;
    if (tid < L_) {
        float mn = s_mean[tid], lv = s_lv[tid];
        s_z[tid] = mn + eps[b * L_ + tid] * expf(0.5f * lv);
        klp = 1.f + lv - mn * mn - expf(lv);
    }
    if (tid < 256) s_red[tid] = klp;
    __syncthreads();
    for (int s = 128; s > 0; s >>= 1) {
        if (tid < s) s_red[tid] += s_red[tid + s];
        __syncthreads();
    }
    if (tid == 0) {
        ws[OFF_KL + b] = s_red[0];
        ((int*)ws)[OFF_CNT + b] = cnt;
        ws[OFF_SQP + b] = 0.f;
    }
    if (tid < 256) {
        float mem = blin[tid];
        for (int l2 = 0; l2 < L_; ++l2) mem = fmaf(s_z[l2], Wlin[l2 * D_ + tid], mem);
        s_mem[tid] = mem;
    }
    __syncthreads();
    if (tid < 256) {
        float qv = bout[tid];
        for (int k = 0; k < D_; ++k) qv = fmaf(s_mem[k], Wout[k * D_ + tid], qv);
        ws[OFF_Q + b * D_ + tid] = qv;
    }
}

// ---- K2: balanced scan, 8 j-range parts per batch row; last block finalizes ----
__global__ __launch_bounds__(256) void scan2(const int* __restrict__ vocab,
                                             const float* __restrict__ emb,
                                             float* __restrict__ ws,
                                             float* __restrict__ out) {
    __shared__ int s_sid[80];
    __shared__ float s_wred[4];
    __shared__ float s_red[256];
    __shared__ int s_prev;
    const int tid = threadIdx.x;
    const int b = blockIdx.x >> 3, part = blockIdx.x & 7;
    const unsigned short* __restrict__ P = (const unsigned short*)(ws + OFF_P);
    float* sqp = ws + OFF_SQP;
    int* done = (int*)ws + 3;
    const int cnt = ((const int*)ws)[OFF_CNT + b];
    const int npos = cnt + 1;
    const int per = (npos + NSPLIT - 1) / NSPLIT;
    const int j0 = part * per;
    const int jend = min(j0 + per, npos);
    const int lo_s = (j0 > 0) ? j0 - 1 : 0;
    const int nstage = min(jend, cnt) - lo_s;  // ids needed: [lo_s, min(jend,cnt))
    // raw vocab == masked id1 on the valid prefix j<cnt
    if (tid < nstage) s_sid[tid] = vocab[b * S_ + lo_s + tid];
    __syncthreads();
    const int jgq = tid >> 6, lane = tid & 63, c = lane * 4;
    const float4 q4 = *(const float4*)(ws + OFF_Q + b * D_ + c);
    float acc = 0.f;
    for (int jj = j0 + jgq * 4; jj < jend; jj += 16) {
        int inp[4], tgt[4];
        float wgt[4];
#pragma unroll
        for (int u = 0; u < 4; ++u) {
            const int j = jj + u;
            const bool v = (j < jend);
            const int jc = v ? j : jj;
            inp[u] = (jc == 0) ? 1 : s_sid[jc - 1 - lo_s];
            tgt[u] = (jc < cnt) ? s_sid[jc - lo_s] : ((cnt < S_) ? 2 : 1);
            wgt[u] = v ? 1.f : 0.f;
        }
        ushort4 pv[4];
        float4 tv[4];
#pragma unroll
        for (int u = 0; u < 4; ++u) {
            pv[u] = *(const ushort4*)(P + (size_t)inp[u] * D_ + c);
            tv[u] = *(const float4*)(emb + (size_t)tgt[u] * D_ + c);
        }
#pragma unroll
        for (int u = 0; u < 4; ++u) {
            float d0 = bf2f(pv[u].x) + q4.x - tv[u].x;
            float d1 = bf2f(pv[u].y) + q4.y - tv[u].y;
            float d2 = bf2f(pv[u].z) + q4.z - tv[u].z;
            float d3 = bf2f(pv[u].w) + q4.w - tv[u].w;
            float s = fmaf(d0, d0, fmaf(d1, d1, fmaf(d2, d2, d3 * d3)));
            acc = fmaf(wgt[u], s, acc);
        }
    }
#pragma unroll
    for (int off = 32; off; off >>= 1) acc += __shfl_down(acc, off, 64);
    if (lane == 0) s_wred[jgq] = acc;
    __syncthreads();
    if (tid == 0) {
        float tot = s_wred[0] + s_wred[1] + s_wred[2] + s_wred[3];
        atomicAdd(&sqp[b], tot);
        __threadfence();
        s_prev = atomicAdd(done, 1);
    }
    __syncthreads();
    if (s_prev == K2B - 1) {
        // final block: reduce sq, kl, valid-count over 256 slots
        s_red[tid] = atomicAdd(&sqp[tid], 0.f);  // coherent read
        __syncthreads();
        for (int s = 128; s > 0; s >>= 1) {
            if (tid < s) s_red[tid] += s_red[tid + s];
            __syncthreads();
        }
        const float sq_tot = s_red[0];
        __syncthreads();
        s_red[tid] = ws[OFF_KL + tid];
        __syncthreads();
        for (int s = 128; s > 0; s >>= 1) {
            if (tid < s) s_red[tid] += s_red[tid + s];
            __syncthreads();
        }
        const float kl_tot = s_red[0];
        __syncthreads();
        s_red[tid] = (float)(((const int*)ws)[OFF_CNT + tid] + 1);
        __syncthreads();
        for (int s = 128; s > 0; s >>= 1) {
            if (tid < s) s_red[tid] += s_red[tid + s];
            __syncthreads();
        }
        if (tid == 0) {
            float denom = s_red[0] * (float)D_;
            if (denom < 1.f) denom = 1.f;
            out[0] = sq_tot / denom;
            out[1] = -0.5f * kl_tot / (float)B_;
        }
    }
}

extern "C" void kernel_launch(void* const* d_in, const int* in_sizes, int n_in,
                              void* d_out, int out_size, void* d_ws, size_t ws_size,
                              hipStream_t stream) {
    const int* vocab = (const int*)d_in[0];
    const int* order = (const int*)d_in[1];
    const int* mask  = (const int*)d_in[2];
    const float* eps  = (const float*)d_in[3];
    const float* emb  = (const float*)d_in[4];
    const float* Wm   = (const float*)d_in[5];
    const float* bm   = (const float*)d_in[6];
    const float* Wv   = (const float*)d_in[7];
    const float* bv   = (const float*)d_in[8];
    const float* Wlin = (const float*)d_in[9];
    const float* blin = (const float*)d_in[10];
    const float* Wout = (const float*)d_in[11];
    const float* bout = (const float*)d_in[12];

    float* ws = (float*)d_ws;
    fused1<<<NENC + NG, 512, 0, stream>>>(vocab, order, mask, emb, eps, Wm, bm,
                                          Wv, bv, Wlin, blin, Wout, bout, ws);
    scan2<<<K2B, 256, 0, stream>>>(vocab, emb, ws, (float*)d_out);
}

// Round 2
// 233.452 us; speedup vs baseline: 1.1603x; 1.1603x over previous
//
#include <hip/hip_runtime.h>

#define B_ 256
#define S_ 512
#define V_ 50000
#define D_ 256
#define L_ 128
#define NGB 512          // gemm blocks (dispatched first = long pole)
#define NENC 256         // enc blocks
#define NCH (V_ / 16)    // 3125 chunks of 16 rows, exact (3125*16 = 50000)
#define NSPLIT 8
#define K2B (B_ * NSPLIT)

typedef __attribute__((ext_vector_type(8))) short short8;
typedef __attribute__((ext_vector_type(4))) float floatx4;

// ws layout (float units):
// [0..16)   ctrl: [3]=done (int)
// [16..272)  sqp[256]
// [272..528) kl[256]
// [528..784) cnt[256] (int)
// [784..784+65536) Q[256][256]
// [66320 .. +6400000) P (50000x256 bf16 = emb @ Wout)
#define OFF_SQP 16
#define OFF_KL  (OFF_SQP + 256)
#define OFF_CNT (OFF_KL + 256)
#define OFF_Q   (OFF_CNT + 256)
#define OFF_P   (OFF_Q + B_ * D_)

__device__ __forceinline__ unsigned short f2bf(float x) {
    unsigned u = __float_as_uint(x);
    u += 0x7FFFu + ((u >> 16) & 1u);
    return (unsigned short)(u >> 16);
}
__device__ __forceinline__ float bf2f(unsigned short u) {
    return __uint_as_float(((unsigned)u) << 16);
}

// ---- K1: GEMM blocks [0,NGB) + enc blocks [NGB, NGB+NENC) ----
__global__ __launch_bounds__(256, 2) void fused1(
    const int* __restrict__ vocab, const int* __restrict__ order,
    const int* __restrict__ mask, const float* __restrict__ emb,
    const float* __restrict__ eps, const float* __restrict__ Wm,
    const float* __restrict__ bm, const float* __restrict__ Wv,
    const float* __restrict__ bv, const float* __restrict__ Wlin,
    const float* __restrict__ blin, const float* __restrict__ Wout,
    const float* __restrict__ bout, float* __restrict__ ws) {
    __shared__ __align__(16) char smem[11904];
    const int tid = threadIdx.x;
    if (blockIdx.x == 0 && tid == 0) ((int*)ws)[3] = 0;  // reset scan2's done ctr

    if (blockIdx.x < NGB) {
        // ============ GEMM role: P = bf16(emb) @ bf16(Wout), convert-once ============
        unsigned short* __restrict__ P = (unsigned short*)(ws + OFF_P);
        const int lane = tid & 63, wv = tid >> 6;
        const int lo = lane & 15, hi = lane >> 4;
        // B fragments from f32 Wout (one-time; 4-segment coalesced per instr, L2-hot)
        short8 bfr[4][8];
#pragma unroll
        for (int nt = 0; nt < 4; ++nt)
#pragma unroll
            for (int kk = 0; kk < 8; ++kk) {
                const float* wp = Wout + (size_t)(hi * 8 + kk * 32) * D_ +
                                  wv * 64 + nt * 16 + lo;
                short8 w;
#pragma unroll
                for (int e = 0; e < 8; ++e) w[e] = (short)f2bf(wp[(size_t)e * D_]);
                bfr[nt][kk] = w;
            }
        int ch = blockIdx.x;
        float4 R[4];
        {
            const float4* src = (const float4*)emb + (size_t)ch * 1024;
#pragma unroll
            for (int i = 0; i < 4; ++i) R[i] = src[i * 256 + tid];
        }
        for (; ch < NCH; ch += NGB) {
            // stage current chunk: f32 regs -> bf16 LDS (swizzled), convert ONCE
#pragma unroll
            for (int i = 0; i < 4; ++i) {
                const int e = (i * 256 + tid) * 4;        // element index in 16x256 tile
                const int row = e >> 8, colb = (e & 255) * 2;
                const int byt = (row * 512 + colb) ^ ((row & 7) << 4);
                ushort4 h;
                h.x = f2bf(R[i].x); h.y = f2bf(R[i].y);
                h.z = f2bf(R[i].z); h.w = f2bf(R[i].w);
                *(ushort4*)(smem + byt) = h;
            }
            __syncthreads();
            // prefetch next chunk's f32 tile into regs (overlaps LDS reads + MFMA)
            const int chn = ch + NGB;
            float4 Rn[4] = {R[0], R[1], R[2], R[3]};
            if (chn < NCH) {
                const float4* src = (const float4*)emb + (size_t)chn * 1024;
#pragma unroll
                for (int i = 0; i < 4; ++i) Rn[i] = src[i * 256 + tid];
            }
            floatx4 acc[4];
#pragma unroll
            for (int nt = 0; nt < 4; ++nt) acc[nt] = (floatx4){0.f, 0.f, 0.f, 0.f};
#pragma unroll
            for (int kk = 0; kk < 8; ++kk) {
                const int byt = (lo * 512 + hi * 16 + kk * 64) ^ ((lo & 7) << 4);
                short8 a = *(const short8*)(smem + byt);
#pragma unroll
                for (int nt = 0; nt < 4; ++nt)
                    acc[nt] = __builtin_amdgcn_mfma_f32_16x16x32_bf16(
                        a, bfr[nt][kk], acc[nt], 0, 0, 0);
            }
#pragma unroll
            for (int r = 0; r < 4; ++r) {
                unsigned short* prow =
                    P + (size_t)(ch * 16 + hi * 4 + r) * D_ + wv * 64 + lo;
#pragma unroll
                for (int nt = 0; nt < 4; ++nt) prow[nt * 16] = f2bf(acc[nt][r]);
            }
            __syncthreads();   // protect LDS before next chunk's writes
#pragma unroll
            for (int i = 0; i < 4; ++i) R[i] = Rn[i];
        }
        return;
    }
    // ============ ENC role: phases 1-3, f32 emb gathers, 256 threads ============
    int* s_id1 = (int*)smem;                    // [512]
    int* s_id2 = s_id1 + S_;                    // [512]
    float4* s_part = (float4*)(smem + 4096);    // [3*64]
    float* s_enc = (float*)(smem + 7168);       // [256]
    float* s_mean = (float*)(smem + 8192);      // [128]
    float* s_lv = (float*)(smem + 8704);        // [128]
    float* s_z = (float*)(smem + 9216);         // [128]
    float* s_mem = (float*)(smem + 9728);       // [256]
    float* s_red = (float*)(smem + 10752);      // [256]
    int* s_cntp = (int*)(smem + 11776);
    const int b = blockIdx.x - NGB;
    if (tid == 0) *s_cntp = 0;
    __syncthreads();
    // phase 1: ids + cnt
    for (int j = tid; j < S_; j += 256) {
        const int mk = mask[b * S_ + j];
        int id1 = 0, id2 = 0;
        if (mk) {
            id1 = vocab[b * S_ + j];
            if (j == 0) {
                id2 = 1;  // BOS
            } else {
                int oi = order[(size_t)(b * S_ + j) * 6];
                if (oi == -1) oi = 1;
                id2 = mask[b * S_ + oi] ? vocab[b * S_ + oi] : 0;
            }
        }
        s_id1[j] = id1;
        s_id2[j] = id2;
        unsigned long long bal = __ballot(mk != 0);
        if ((tid & 63) == 0) atomicAdd(s_cntp, __popcll(bal));
    }
    __syncthreads();
    const int cnt = *s_cntp;
    // phase 2: mean of emb[id1]+emb[id2] over valid prefix (row-contiguous gathers)
    const int jg = tid >> 6, d4 = tid & 63;
    const float4* eb4 = (const float4*)emb;
    float4 a = {0.f, 0.f, 0.f, 0.f};
#pragma unroll 4
    for (int j = jg; j < cnt; j += 4) {
        float4 x = eb4[(size_t)s_id1[j] * 64 + d4];
        float4 y = eb4[(size_t)s_id2[j] * 64 + d4];
        a.x += x.x + y.x; a.y += x.y + y.y;
        a.z += x.z + y.z; a.w += x.w + y.w;
    }
    if (jg) s_part[(jg - 1) * 64 + d4] = a;
    __syncthreads();
    if (jg == 0) {
#pragma unroll
        for (int g = 0; g < 3; ++g) {
            float4 p = s_part[g * 64 + d4];
            a.x += p.x; a.y += p.y; a.z += p.z; a.w += p.w;
        }
        const float inv = 1.f / fmaxf((float)cnt, 1.f);
        a.x *= inv; a.y *= inv; a.z *= inv; a.w *= inv;
        ((float4*)s_enc)[d4] = a;
    }
    __syncthreads();
    // phase 3: latent chain -> Q[b], kl[b], cnt[b]
    {
        const int l = tid & (L_ - 1);
        const float* W = (tid < L_) ? Wm : Wv;
        const float* bb = (tid < L_) ? bm : bv;
        float dot = bb[l];
        for (int d = 0; d < D_; ++d) dot = fmaf(s_enc[d], W[d * L_ + l], dot);
        if (tid < L_) s_mean[l] = dot; else s_lv[l] = dot;
    }
    __syncthreads();
    float klp = 0.f;
    if (tid < L_) {
        float mn = s_mean[tid], lv = s_lv[tid];
        s_z[tid] = mn + eps[b * L_ + tid] * expf(0.5f * lv);
        klp = 1.f + lv - mn * mn - expf(lv);
    }
    s_red[tid] = klp;
    __syncthreads();
    for (int s = 128; s > 0; s >>= 1) {
        if (tid < s) s_red[tid] += s_red[tid + s];
        __syncthreads();
    }
    if (tid == 0) {
        ws[OFF_KL + b] = s_red[0];
        ((int*)ws)[OFF_CNT + b] = cnt;
        ws[OFF_SQP + b] = 0.f;
    }
    {
        float mem = blin[tid];
        for (int l2 = 0; l2 < L_; ++l2) mem = fmaf(s_z[l2], Wlin[l2 * D_ + tid], mem);
        s_mem[tid] = mem;
    }
    __syncthreads();
    {
        float qv = bout[tid];
        for (int k = 0; k < D_; ++k) qv = fmaf(s_mem[k], Wout[k * D_ + tid], qv);
        ws[OFF_Q + b * D_ + tid] = qv;
    }
}

// ---- K2: balanced scan, 8 j-range parts per batch row; last block finalizes ----
__global__ __launch_bounds__(256) void scan2(const int* __restrict__ vocab,
                                             const float* __restrict__ emb,
                                             float* __restrict__ ws,
                                             float* __restrict__ out) {
    __shared__ int s_sid[80];
    __shared__ float s_wred[4];
    __shared__ float s_red[256];
    __shared__ int s_prev;
    const int tid = threadIdx.x;
    const int b = blockIdx.x >> 3, part = blockIdx.x & 7;
    const unsigned short* __restrict__ P = (const unsigned short*)(ws + OFF_P);
    float* sqp = ws + OFF_SQP;
    int* done = (int*)ws + 3;
    const int cnt = ((const int*)ws)[OFF_CNT + b];
    const int npos = cnt + 1;
    const int per = (npos + NSPLIT - 1) / NSPLIT;
    const int j0 = part * per;
    const int jend = min(j0 + per, npos);
    const int lo_s = (j0 > 0) ? j0 - 1 : 0;
    const int nstage = min(jend, cnt) - lo_s;  // ids needed: [lo_s, min(jend,cnt))
    // raw vocab == masked id1 on the valid prefix j<cnt
    if (tid < nstage) s_sid[tid] = vocab[b * S_ + lo_s + tid];
    __syncthreads();
    const int jgq = tid >> 6, lane = tid & 63, c = lane * 4;
    const float4 q4 = *(const float4*)(ws + OFF_Q + b * D_ + c);
    float acc = 0.f;
    for (int jj = j0 + jgq * 4; jj < jend; jj += 16) {
        int inp[4], tgt[4];
        float wgt[4];
#pragma unroll
        for (int u = 0; u < 4; ++u) {
            const int j = jj + u;
            const bool v = (j < jend);
            const int jc = v ? j : jj;
            inp[u] = (jc == 0) ? 1 : s_sid[jc - 1 - lo_s];
            tgt[u] = (jc < cnt) ? s_sid[jc - lo_s] : ((cnt < S_) ? 2 : 1);
            wgt[u] = v ? 1.f : 0.f;
        }
        ushort4 pv[4];
        float4 tv[4];
#pragma unroll
        for (int u = 0; u < 4; ++u) {
            pv[u] = *(const ushort4*)(P + (size_t)inp[u] * D_ + c);
            tv[u] = *(const float4*)(emb + (size_t)tgt[u] * D_ + c);
        }
#pragma unroll
        for (int u = 0; u < 4; ++u) {
            float d0 = bf2f(pv[u].x) + q4.x - tv[u].x;
            float d1 = bf2f(pv[u].y) + q4.y - tv[u].y;
            float d2 = bf2f(pv[u].z) + q4.z - tv[u].z;
            float d3 = bf2f(pv[u].w) + q4.w - tv[u].w;
            float s = fmaf(d0, d0, fmaf(d1, d1, fmaf(d2, d2, d3 * d3)));
            acc = fmaf(wgt[u], s, acc);
        }
    }
#pragma unroll
    for (int off = 32; off; off >>= 1) acc += __shfl_down(acc, off, 64);
    if (lane == 0) s_wred[jgq] = acc;
    __syncthreads();
    if (tid == 0) {
        float tot = s_wred[0] + s_wred[1] + s_wred[2] + s_wred[3];
        atomicAdd(&sqp[b], tot);
        __threadfence();
        s_prev = atomicAdd(done, 1);
    }
    __syncthreads();
    if (s_prev == K2B - 1) {
        s_red[tid] = atomicAdd(&sqp[tid], 0.f);  // coherent read
        __syncthreads();
        for (int s = 128; s > 0; s >>= 1) {
            if (tid < s) s_red[tid] += s_red[tid + s];
            __syncthreads();
        }
        const float sq_tot = s_red[0];
        __syncthreads();
        s_red[tid] = ws[OFF_KL + tid];
        __syncthreads();
        for (int s = 128; s > 0; s >>= 1) {
            if (tid < s) s_red[tid] += s_red[tid + s];
            __syncthreads();
        }
        const float kl_tot = s_red[0];
        __syncthreads();
        s_red[tid] = (float)(((const int*)ws)[OFF_CNT + tid] + 1);
        __syncthreads();
        for (int s = 128; s > 0; s >>= 1) {
            if (tid < s) s_red[tid] += s_red[tid + s];
            __syncthreads();
        }
        if (tid == 0) {
            float denom = s_red[0] * (float)D_;
            if (denom < 1.f) denom = 1.f;
            out[0] = sq_tot / denom;
            out[1] = -0.5f * kl_tot / (float)B_;
        }
    }
}

extern "C" void kernel_launch(void* const* d_in, const int* in_sizes, int n_in,
                              void* d_out, int out_size, void* d_ws, size_t ws_size,
                              hipStream_t stream) {
    const int* vocab = (const int*)d_in[0];
    const int* order = (const int*)d_in[1];
    const int* mask  = (const int*)d_in[2];
    const float* eps  = (const float*)d_in[3];
    const float* emb  = (const float*)d_in[4];
    const float* Wm   = (const float*)d_in[5];
    const float* bm   = (const float*)d_in[6];
    const float* Wv   = (const float*)d_in[7];
    const float* bv   = (const float*)d_in[8];
    const float* Wlin = (const float*)d_in[9];
    const float* blin = (const float*)d_in[10];
    const float* Wout = (const float*)d_in[11];
    const float* bout = (const float*)d_in[12];

    float* ws = (float*)d_ws;
    fused1<<<NGB + NENC, 256, 0, stream>>>(vocab, order, mask, emb, eps, Wm, bm,
                                           Wv, bv, Wlin, blin, Wout, bout, ws);
    scan2<<<K2B, 256, 0, stream>>>(vocab, emb, ws, (float*)d_out);
}

// Round 4
// 172.037 us; speedup vs baseline: 1.5746x; 1.3570x over previous
//
#include <hip/hip_runtime.h>

#define B_ 256
#define S_ 512
#define V_ 50000
#define D_ 256
#define L_ 128
#define NGB 512          // gemm blocks (dispatched first = long pole)
#define NENC 256         // enc blocks
#define NCH (V_ / 16)    // 3125 chunks of 16 rows, exact (3125*16 = 50000)
#define NSPLIT 8
#define K2B (B_ * NSPLIT)

typedef __attribute__((ext_vector_type(8))) short short8;
typedef __attribute__((ext_vector_type(4))) float floatx4;

// ws layout (float units):
// [16..2064)   sqp2[2048]  (one exclusive slot per scan2 block, plain stores)
// [2064..2320) kl[256]
// [2320..2576) cnt[256] (int)
// [2576..68112) Q[256][256]
// [68112 .. +6400000) P (50000x256 bf16 = emb @ Wout)
#define OFF_SQP 16
#define OFF_KL  (OFF_SQP + K2B)
#define OFF_CNT (OFF_KL + 256)
#define OFF_Q   (OFF_CNT + 256)
#define OFF_P   (OFF_Q + B_ * D_)

__device__ __forceinline__ unsigned short f2bf(float x) {
    unsigned u = __float_as_uint(x);
    u += 0x7FFFu + ((u >> 16) & 1u);
    return (unsigned short)(u >> 16);
}
__device__ __forceinline__ float bf2f(unsigned short u) {
    return __uint_as_float(((unsigned)u) << 16);
}

// ---- K1: GEMM blocks [0,NGB) + enc blocks [NGB, NGB+NENC) ----
__global__ __launch_bounds__(256, 2) void fused1(
    const int* __restrict__ vocab, const int* __restrict__ order,
    const int* __restrict__ mask, const float* __restrict__ emb,
    const float* __restrict__ eps, const float* __restrict__ Wm,
    const float* __restrict__ bm, const float* __restrict__ Wv,
    const float* __restrict__ bv, const float* __restrict__ Wlin,
    const float* __restrict__ blin, const float* __restrict__ Wout,
    const float* __restrict__ bout, float* __restrict__ ws) {
    __shared__ __align__(16) char smem[11904];
    const int tid = threadIdx.x;

    if (blockIdx.x < NGB) {
        // ============ GEMM role: P = bf16(emb) @ bf16(Wout), convert-once ============
        unsigned short* __restrict__ P = (unsigned short*)(ws + OFF_P);
        const int lane = tid & 63, wv = tid >> 6;
        const int lo = lane & 15, hi = lane >> 4;
        // B fragments from f32 Wout (one-time; L2-hot after first blocks)
        short8 bfr[4][8];
#pragma unroll
        for (int nt = 0; nt < 4; ++nt)
#pragma unroll
            for (int kk = 0; kk < 8; ++kk) {
                const float* wp = Wout + (size_t)(hi * 8 + kk * 32) * D_ +
                                  wv * 64 + nt * 16 + lo;
                short8 w;
#pragma unroll
                for (int e = 0; e < 8; ++e) w[e] = (short)f2bf(wp[(size_t)e * D_]);
                bfr[nt][kk] = w;
            }
        int ch = blockIdx.x;
        float4 R[4];
        {
            const float4* src = (const float4*)emb + (size_t)ch * 1024;
#pragma unroll
            for (int i = 0; i < 4; ++i) R[i] = src[i * 256 + tid];
        }
        for (; ch < NCH; ch += NGB) {
            // stage current chunk: f32 regs -> bf16 LDS (swizzled), convert ONCE
#pragma unroll
            for (int i = 0; i < 4; ++i) {
                const int e = (i * 256 + tid) * 4;        // element index in 16x256 tile
                const int row = e >> 8, colb = (e & 255) * 2;
                const int byt = (row * 512 + colb) ^ ((row & 7) << 4);
                ushort4 h;
                h.x = f2bf(R[i].x); h.y = f2bf(R[i].y);
                h.z = f2bf(R[i].z); h.w = f2bf(R[i].w);
                *(ushort4*)(smem + byt) = h;
            }
            __syncthreads();
            // prefetch next chunk's f32 tile into regs (overlaps LDS reads + MFMA)
            const int chn = ch + NGB;
            float4 Rn[4] = {R[0], R[1], R[2], R[3]};
            if (chn < NCH) {
                const float4* src = (const float4*)emb + (size_t)chn * 1024;
#pragma unroll
                for (int i = 0; i < 4; ++i) Rn[i] = src[i * 256 + tid];
            }
            floatx4 acc[4];
#pragma unroll
            for (int nt = 0; nt < 4; ++nt) acc[nt] = (floatx4){0.f, 0.f, 0.f, 0.f};
#pragma unroll
            for (int kk = 0; kk < 8; ++kk) {
                const int byt = (lo * 512 + hi * 16 + kk * 64) ^ ((lo & 7) << 4);
                short8 a = *(const short8*)(smem + byt);
#pragma unroll
                for (int nt = 0; nt < 4; ++nt)
                    acc[nt] = __builtin_amdgcn_mfma_f32_16x16x32_bf16(
                        a, bfr[nt][kk], acc[nt], 0, 0, 0);
            }
#pragma unroll
            for (int r = 0; r < 4; ++r) {
                unsigned short* prow =
                    P + (size_t)(ch * 16 + hi * 4 + r) * D_ + wv * 64 + lo;
#pragma unroll
                for (int nt = 0; nt < 4; ++nt) prow[nt * 16] = f2bf(acc[nt][r]);
            }
            __syncthreads();   // protect LDS before next chunk's writes
#pragma unroll
            for (int i = 0; i < 4; ++i) R[i] = Rn[i];
        }
        return;
    }
    // ============ ENC role: phases 1-3, f32 emb gathers, 256 threads ============
    int* s_id1 = (int*)smem;                    // [512]
    int* s_id2 = s_id1 + S_;                    // [512]
    float4* s_part = (float4*)(smem + 4096);    // [3*64]
    float* s_enc = (float*)(smem + 7168);       // [256]
    float* s_mean = (float*)(smem + 8192);      // [128]
    float* s_lv = (float*)(smem + 8704);        // [128]
    float* s_z = (float*)(smem + 9216);         // [128]
    float* s_mem = (float*)(smem + 9728);       // [256]
    float* s_red = (float*)(smem + 10752);      // [256]
    int* s_cntp = (int*)(smem + 11776);
    const int b = blockIdx.x - NGB;
    if (tid == 0) *s_cntp = 0;
    __syncthreads();
    // phase 1: ids + cnt
    for (int j = tid; j < S_; j += 256) {
        const int mk = mask[b * S_ + j];
        int id1 = 0, id2 = 0;
        if (mk) {
            id1 = vocab[b * S_ + j];
            if (j == 0) {
                id2 = 1;  // BOS
            } else {
                int oi = order[(size_t)(b * S_ + j) * 6];
                if (oi == -1) oi = 1;
                id2 = mask[b * S_ + oi] ? vocab[b * S_ + oi] : 0;
            }
        }
        s_id1[j] = id1;
        s_id2[j] = id2;
        unsigned long long bal = __ballot(mk != 0);
        if ((tid & 63) == 0) atomicAdd(s_cntp, __popcll(bal));
    }
    __syncthreads();
    const int cnt = *s_cntp;
    // phase 2: mean of emb[id1]+emb[id2] over valid prefix (row-contiguous gathers)
    const int jg = tid >> 6, d4 = tid & 63;
    const float4* eb4 = (const float4*)emb;
    float4 a = {0.f, 0.f, 0.f, 0.f};
#pragma unroll 4
    for (int j = jg; j < cnt; j += 4) {
        float4 x = eb4[(size_t)s_id1[j] * 64 + d4];
        float4 y = eb4[(size_t)s_id2[j] * 64 + d4];
        a.x += x.x + y.x; a.y += x.y + y.y;
        a.z += x.z + y.z; a.w += x.w + y.w;
    }
    if (jg) s_part[(jg - 1) * 64 + d4] = a;
    __syncthreads();
    if (jg == 0) {
#pragma unroll
        for (int g = 0; g < 3; ++g) {
            float4 p = s_part[g * 64 + d4];
            a.x += p.x; a.y += p.y; a.z += p.z; a.w += p.w;
        }
        const float inv = 1.f / fmaxf((float)cnt, 1.f);
        a.x *= inv; a.y *= inv; a.z *= inv; a.w *= inv;
        ((float4*)s_enc)[d4] = a;
    }
    __syncthreads();
    // phase 3: latent chain -> Q[b], kl[b], cnt[b]
    {
        const int l = tid & (L_ - 1);
        const float* W = (tid < L_) ? Wm : Wv;
        const float* bb = (tid < L_) ? bm : bv;
        float dot = bb[l];
        for (int d = 0; d < D_; ++d) dot = fmaf(s_enc[d], W[d * L_ + l], dot);
        if (tid < L_) s_mean[l] = dot; else s_lv[l] = dot;
    }
    __syncthreads();
    float klp = 0.f;
    if (tid < L_) {
        float mn = s_mean[tid], lv = s_lv[tid];
        s_z[tid] = mn + eps[b * L_ + tid] * expf(0.5f * lv);
        klp = 1.f + lv - mn * mn - expf(lv);
    }
    s_red[tid] = klp;
    __syncthreads();
    for (int s = 128; s > 0; s >>= 1) {
        if (tid < s) s_red[tid] += s_red[tid + s];
        __syncthreads();
    }
    if (tid == 0) {
        ws[OFF_KL + b] = s_red[0];
        ((int*)ws)[OFF_CNT + b] = cnt;
    }
    {
        float mem = blin[tid];
        for (int l2 = 0; l2 < L_; ++l2) mem = fmaf(s_z[l2], Wlin[l2 * D_ + tid], mem);
        s_mem[tid] = mem;
    }
    __syncthreads();
    {
        float qv = bout[tid];
        for (int k = 0; k < D_; ++k) qv = fmaf(s_mem[k], Wout[k * D_ + tid], qv);
        ws[OFF_Q + b * D_ + tid] = qv;
    }
}

// ---- K2: balanced scan; NO atomics — exclusive partial slot per block ----
__global__ __launch_bounds__(256) void scan2(const int* __restrict__ vocab,
                                             const float* __restrict__ emb,
                                             float* __restrict__ ws) {
    __shared__ int s_sid[80];
    __shared__ float s_wred[4];
    const int tid = threadIdx.x;
    const int b = blockIdx.x >> 3, part = blockIdx.x & 7;
    const unsigned short* __restrict__ P = (const unsigned short*)(ws + OFF_P);
    const int cnt = ((const int*)ws)[OFF_CNT + b];
    const int npos = cnt + 1;
    const int per = (npos + NSPLIT - 1) / NSPLIT;
    const int j0 = part * per;
    const int jend = min(j0 + per, npos);
    const int lo_s = (j0 > 0) ? j0 - 1 : 0;
    const int nstage = min(jend, cnt) - lo_s;  // ids needed: [lo_s, min(jend,cnt))
    // raw vocab == masked id1 on the valid prefix j<cnt
    if (tid < nstage) s_sid[tid] = vocab[b * S_ + lo_s + tid];
    __syncthreads();
    const int jgq = tid >> 6, lane = tid & 63, c = lane * 4;
    const float4 q4 = *(const float4*)(ws + OFF_Q + b * D_ + c);
    float acc = 0.f;
    for (int jj = j0 + jgq * 4; jj < jend; jj += 16) {
        int inp[4], tgt[4];
        float wgt[4];
#pragma unroll
        for (int u = 0; u < 4; ++u) {
            const int j = jj + u;
            const bool v = (j < jend);
            const int jc = v ? j : jj;
            inp[u] = (jc == 0) ? 1 : s_sid[jc - 1 - lo_s];
            tgt[u] = (jc < cnt) ? s_sid[jc - lo_s] : ((cnt < S_) ? 2 : 1);
            wgt[u] = v ? 1.f : 0.f;
        }
        ushort4 pv[4];
        float4 tv[4];
#pragma unroll
        for (int u = 0; u < 4; ++u) {
            pv[u] = *(const ushort4*)(P + (size_t)inp[u] * D_ + c);
            tv[u] = *(const float4*)(emb + (size_t)tgt[u] * D_ + c);
        }
#pragma unroll
        for (int u = 0; u < 4; ++u) {
            float d0 = bf2f(pv[u].x) + q4.x - tv[u].x;
            float d1 = bf2f(pv[u].y) + q4.y - tv[u].y;
            float d2 = bf2f(pv[u].z) + q4.z - tv[u].z;
            float d3 = bf2f(pv[u].w) + q4.w - tv[u].w;
            float s = fmaf(d0, d0, fmaf(d1, d1, fmaf(d2, d2, d3 * d3)));
            acc = fmaf(wgt[u], s, acc);
        }
    }
#pragma unroll
    for (int off = 32; off; off >>= 1) acc += __shfl_down(acc, off, 64);
    if (lane == 0) s_wred[jgq] = acc;
    __syncthreads();
    if (tid == 0)
        ws[OFF_SQP + blockIdx.x] = s_wred[0] + s_wred[1] + s_wred[2] + s_wred[3];
}

// ---- K3: single-block finalize (reduces 2048 sq partials + kl + cnt) ----
__global__ __launch_bounds__(256) void finalize3(const float* __restrict__ ws,
                                                 float* __restrict__ out) {
    __shared__ float s_red[256];
    const int tid = threadIdx.x;
    float sq = 0.f;
#pragma unroll
    for (int i = 0; i < NSPLIT; ++i) sq += ws[OFF_SQP + i * 256 + tid];
    s_red[tid] = sq;
    __syncthreads();
    for (int s = 128; s > 0; s >>= 1) {
        if (tid < s) s_red[tid] += s_red[tid + s];
        __syncthreads();
    }
    const float sq_tot = s_red[0];
    __syncthreads();
    s_red[tid] = ws[OFF_KL + tid];
    __syncthreads();
    for (int s = 128; s > 0; s >>= 1) {
        if (tid < s) s_red[tid] += s_red[tid + s];
        __syncthreads();
    }
    const float kl_tot = s_red[0];
    __syncthreads();
    s_red[tid] = (float)(((const int*)ws)[OFF_CNT + tid] + 1);
    __syncthreads();
    for (int s = 128; s > 0; s >>= 1) {
        if (tid < s) s_red[tid] += s_red[tid + s];
        __syncthreads();
    }
    if (tid == 0) {
        float denom = s_red[0] * (float)D_;
        if (denom < 1.f) denom = 1.f;
        out[0] = sq_tot / denom;
        out[1] = -0.5f * kl_tot / (float)B_;
    }
}

extern "C" void kernel_launch(void* const* d_in, const int* in_sizes, int n_in,
                              void* d_out, int out_size, void* d_ws, size_t ws_size,
                              hipStream_t stream) {
    const int* vocab = (const int*)d_in[0];
    const int* order = (const int*)d_in[1];
    const int* mask  = (const int*)d_in[2];
    const float* eps  = (const float*)d_in[3];
    const float* emb  = (const float*)d_in[4];
    const float* Wm   = (const float*)d_in[5];
    const float* bm   = (const float*)d_in[6];
    const float* Wv   = (const float*)d_in[7];
    const float* bv   = (const float*)d_in[8];
    const float* Wlin = (const float*)d_in[9];
    const float* blin = (const float*)d_in[10];
    const float* Wout = (const float*)d_in[11];
    const float* bout = (const float*)d_in[12];

    float* ws = (float*)d_ws;
    fused1<<<NGB + NENC, 256, 0, stream>>>(vocab, order, mask, emb, eps, Wm, bm,
                                           Wv, bv, Wlin, blin, Wout, bout, ws);
    scan2<<<K2B, 256, 0, stream>>>(vocab, emb, ws);
    finalize3<<<1, 256, 0, stream>>>(ws, (float*)d_out);
}